// Round 6
// baseline (133.625 us; speedup 1.0000x reference)
//
#include <hip/hip_runtime.h>
#include <cstdint>

#define B_SZ   4
#define E_DIM  16
#define C_INST 24
#define HW_N   262144          // 512*512
#define NG     (HW_N / 4)      // 65536 float4 pixel-groups per (b, e)

#define DELTA_VAR  0.75f
#define DELTA_DIST 2.0f
#define ALPHA_W 1.0f
#define BETA_W  1.0f
#define GAMMA_W 0.001f

#define P1_NB   16                       // chunks per (plane, b)
#define P1_ITER (NG / (P1_NB * 256))     // 16
#define ROW_STRIDE 51                    // 2*24 + 3 pad, odd -> banks spread

// ---------------------------------------------------------------------------
// Pass 1: lane-private LDS bucket segment-sums, TWO dims per plane.
// Each block: dims (2*eg2, 2*eg2+1); labels loaded once feed both dims at
// adjacent LDS words (mergeable into ds_*2_b32). Counts folded in via
// __ballot/popc on iterations it>>1 == eg2 (each slice counted exactly once
// across the 8 planes; ballot is wave-uniform -> SGPR accumulators).
// Label traffic: 17 sweeps (R4) -> 8. No occupancy cap (R3 spill lesson).
// ---------------------------------------------------------------------------
__global__ __launch_bounds__(256) void pass1_kernel(
    const float* __restrict__ input, const int* __restrict__ target,
    float* __restrict__ sums, float* __restrict__ counts)
{
    __shared__ float buk[256][ROW_STRIDE];
    __shared__ float crow[4][C_INST];
    const int tid  = threadIdx.x;
    const int lane = tid & 63;
    const int wv   = tid >> 6;
    const int chunk = blockIdx.x;
    const int eg2   = blockIdx.y;        // 0..7 -> dims 2*eg2, 2*eg2+1
    const int b     = blockIdx.z;

    float* __restrict__ myrow = &buk[tid][0];
    #pragma unroll
    for (int j = 0; j < 2 * C_INST; ++j) myrow[j] = 0.f;  // own row: no sync

    const int4* __restrict__ tgt4 = (const int4*)(target + (size_t)b * HW_N);
    const float4* __restrict__ s0 =
        (const float4*)(input + ((size_t)b * E_DIM + 2 * eg2) * HW_N);
    const float4* __restrict__ s1 =
        (const float4*)(input + ((size_t)b * E_DIM + 2 * eg2 + 1) * HW_N);
    const int gbase = chunk * 256 * P1_ITER + tid;

    int scnt[C_INST];
    #pragma unroll
    for (int c = 0; c < C_INST; ++c) scnt[c] = 0;

    int4   lab = tgt4[gbase];
    float4 xa  = s0[gbase];
    float4 xb  = s1[gbase];
    #pragma unroll
    for (int it = 0; it < P1_ITER; ++it) {
        const int4   lc  = lab;
        const float4 xa0 = xa;
        const float4 xb0 = xb;
        if (it + 1 < P1_ITER) {          // register prefetch
            lab = tgt4[gbase + (it + 1) * 256];
            xa  = s0[gbase + (it + 1) * 256];
            xb  = s1[gbase + (it + 1) * 256];
        }
        // adjacent-pair RMW: dims d=0,1 at myrow[2c], myrow[2c+1]
        myrow[2 * lc.x]     += xa0.x;
        myrow[2 * lc.x + 1] += xb0.x;
        myrow[2 * lc.y]     += xa0.y;
        myrow[2 * lc.y + 1] += xb0.y;
        myrow[2 * lc.z]     += xa0.z;
        myrow[2 * lc.z + 1] += xb0.z;
        myrow[2 * lc.w]     += xa0.w;
        myrow[2 * lc.w + 1] += xb0.w;

        if ((it >> 1) == eg2) {          // uniform: this plane counts 2 slices
            #pragma unroll
            for (int c = 0; c < C_INST; ++c) {
                scnt[c] += (int)__popcll(__ballot(lc.x == c))
                         + (int)__popcll(__ballot(lc.y == c))
                         + (int)__popcll(__ballot(lc.z == c))
                         + (int)__popcll(__ballot(lc.w == c));
            }
        }
    }
    if (lane == 0) {
        #pragma unroll
        for (int c = 0; c < C_INST; ++c) crow[wv][c] = (float)scnt[c];
    }
    __syncthreads();

    // reduce 256 bucket rows -> 48 (d,c) sums; 4 threads per value
    if (tid < 4 * 2 * C_INST) {
        const int j  = tid >> 2;         // 0..47 = 2*c + d
        const int r0 = tid & 3;
        float s = 0.f;
        #pragma unroll
        for (int i = 0; i < 64; ++i) s += buk[4 * i + r0][j];
        s += __shfl_xor(s, 1, 64);
        s += __shfl_xor(s, 2, 64);
        if (r0 == 0) {
            const int c = j >> 1, d = j & 1;
            unsafeAtomicAdd(&sums[((size_t)b * E_DIM + 2 * eg2 + d) * C_INST + c], s);
        }
    }
    if (tid < C_INST) {
        const float s = crow[0][tid] + crow[1][tid] + crow[2][tid] + crow[3][tid];
        unsafeAtomicAdd(&counts[b * C_INST + tid], s);
    }
}

// ---------------------------------------------------------------------------
// Pass 2: variance term as ONE scalar: sum of h^2 / cnt[lab]. mu in LDS
// [c][20]; one float4 pixel-group per thread; scalar butterfly; 1 atomic/block.
// ---------------------------------------------------------------------------
__global__ __launch_bounds__(256) void pass2_kernel(
    const float* __restrict__ input, const int* __restrict__ target,
    const float* __restrict__ sums, const float* __restrict__ counts,
    float* __restrict__ loss_acc)
{
    __shared__ float mu_l[C_INST][20];
    __shared__ float w_l[C_INST];
    __shared__ float redw[4];
    const int tid  = threadIdx.x;
    const int lane = tid & 63;
    const int wv   = tid >> 6;
    const int b    = blockIdx.y;

    if (tid < C_INST) {
        const float cv = counts[b * C_INST + tid];
        w_l[tid] = (cv > 0.f) ? 1.f / cv : 0.f;
    }
    __syncthreads();
    for (int i = tid; i < E_DIM * C_INST; i += 256) {
        const int e = i / C_INST, c = i % C_INST;
        mu_l[c][e] = sums[((size_t)b * E_DIM + e) * C_INST + c] * w_l[c];
    }
    __syncthreads();

    const int g = blockIdx.x * 256 + tid;    // 256 blocks/batch * 256 = 65536
    const int4 lab4 = ((const int4*)(target + (size_t)b * HW_N))[g];
    const int lp[4] = {lab4.x, lab4.y, lab4.z, lab4.w};

    const float4* __restrict__ src4 = (const float4*)(input + (size_t)b * E_DIM * HW_N);
    float xs[E_DIM * 4];
    #pragma unroll
    for (int e = 0; e < E_DIM; ++e)
        ((float4*)xs)[e] = src4[(size_t)e * NG + g];

    float vloc = 0.f;
    #pragma unroll
    for (int p = 0; p < 4; ++p) {
        const int c = lp[p];
        float d2 = 0.f;
        #pragma unroll
        for (int e = 0; e < E_DIM; ++e) {
            const float df = xs[e * 4 + p] - mu_l[c][e];
            d2 = fmaf(df, df, d2);
        }
        const float h = fmaxf(sqrtf(d2) - DELTA_VAR, 0.f);
        vloc = fmaf(h * h, w_l[c], vloc);
    }

    #pragma unroll
    for (int m = 1; m < 64; m <<= 1) vloc += __shfl_xor(vloc, m, 64);
    if (lane == 0) redw[wv] = vloc;
    __syncthreads();
    if (tid == 0)
        unsafeAtomicAdd(loss_acc, redw[0] + redw[1] + redw[2] + redw[3]);
}

// ---------------------------------------------------------------------------
// Final: pairwise distance + regularizer + variance scalar -> loss.
// ---------------------------------------------------------------------------
__global__ __launch_bounds__(256) void final_kernel(
    const float* __restrict__ sums, const float* __restrict__ counts,
    const float* __restrict__ loss_acc, float* __restrict__ out)
{
    __shared__ float mu[B_SZ][C_INST][E_DIM];
    __shared__ float red[256];
    const int tid = threadIdx.x;

    for (int i = tid; i < B_SZ * C_INST * E_DIM; i += 256) {
        const int b = i / (C_INST * E_DIM);
        const int r = i % (C_INST * E_DIM);
        const int e = r / C_INST, c = r % C_INST;
        const float cv = counts[b * C_INST + c];
        mu[b][c][e] = (cv > 0.f)
            ? sums[((size_t)b * E_DIM + e) * C_INST + c] / cv : 0.f;
    }
    __syncthreads();

    float acc = 0.f;
    for (int i = tid; i < B_SZ * C_INST; i += 256) {
        const int b = i / C_INST, c = i % C_INST;
        float n2 = 0.f;
        #pragma unroll
        for (int e = 0; e < E_DIM; ++e) n2 += mu[b][c][e] * mu[b][c][e];
        acc += GAMMA_W * sqrtf(n2) * (1.0f / (B_SZ * C_INST));
    }
    for (int i = tid; i < B_SZ * C_INST * C_INST; i += 256) {
        const int b  = i / (C_INST * C_INST);
        const int r  = i % (C_INST * C_INST);
        const int c1 = r / C_INST, c2 = r % C_INST;
        if (c1 != c2) {
            float d2 = 0.f;
            #pragma unroll
            for (int e = 0; e < E_DIM; ++e) {
                const float d = mu[b][c1][e] - mu[b][c2][e];
                d2 += d * d;
            }
            const float h = fmaxf(2.0f * DELTA_DIST - sqrtf(d2), 0.f);
            acc += BETA_W * h * h * (1.0f / (B_SZ * C_INST * (C_INST - 1)));
        }
    }

    red[tid] = acc;
    __syncthreads();
    for (int s = 128; s > 0; s >>= 1) {
        if (tid < s) red[tid] += red[tid + s];
        __syncthreads();
    }
    if (tid == 0)
        out[0] = red[0] + ALPHA_W * loss_acc[0] * (1.0f / (B_SZ * C_INST));
}

extern "C" void kernel_launch(void* const* d_in, const int* in_sizes, int n_in,
                              void* d_out, int out_size, void* d_ws, size_t ws_size,
                              hipStream_t stream)
{
    const float* input  = (const float*)d_in[0];
    const int*   target = (const int*)d_in[1];

    float* sums     = (float*)d_ws;                         // B*E*C ([b][e][c])
    float* counts   = sums + B_SZ * E_DIM * C_INST;         // B*C
    float* loss_acc = counts + B_SZ * C_INST;               // 1
    const size_t ws_bytes =
        (size_t)(B_SZ * E_DIM * C_INST + B_SZ * C_INST + 1) * sizeof(float);
    hipMemsetAsync(d_ws, 0, ws_bytes, stream);

    pass1_kernel<<<dim3(P1_NB, E_DIM / 2, B_SZ), 256, 0, stream>>>(input, target, sums, counts);
    pass2_kernel<<<dim3(NG / 256, B_SZ), 256, 0, stream>>>(input, target, sums, counts, loss_acc);
    final_kernel<<<1, 256, 0, stream>>>(sums, counts, loss_acc, (float*)d_out);
}